// Round 1
// baseline (511.748 us; speedup 1.0000x reference)
//
#include <hip/hip_runtime.h>

// EnhancedReconstructionLoss: loss = 0.8*mean((x-y)^2) + 0.2*(1 - mean(ssim_map))
// ssim from 3x3 avg pools (stride 1, zero-pad 1, divisor always 9).
// Shapes: (32,3,512,512) fp32 -> 96 planes of 512x512.
//
// R2: atomics -> per-block partial stores (639 -> 101 us main).
// R3: parallel 2-stage reduce; rcp not divide (96 us).
// R4: 64x64 f32 LDS tile, 4x4/thread (91 us).
// R6: f16 LDS staging (19 KB/block -> 8 blocks/CU). 89 us, VALUBusy 43%.
// R8 (this): attack register starvation + staging serialization:
//   - fuse s_xx+s_yy into one quantity (SSIM only needs the sum)
//   - ring of row-sums packed f16 (half2 ring[3][4][2] = 24 VGPR vs 60 f32),
//     compile-time j%3 rotation (no h0/h1 copy chain); vertical sums v_pk_add_f16
//   - staging: uniform 5 fully-unrolled iters, all 10 float4 loads batched
//     into regs before any cvt/ds_write (loads pipelined, not serialized)
//   - last-block-done fused finish: drops loss_reduce1/loss_final launches.
//     Counter reset via 4B hipMemsetAsync each launch (graph-capture safe).

#define PLANE_H 512
#define PLANE_W 512
#define NPLANES 96
#define TILE    64
#define LDSH    66                  // TILE + 2 halo rows
#define LDSW    72                  // halfs/row; 144 B stride
#define NQUADS  (LDSH * 18)         // 1188 float4-quads
#define NBLOCKS ((PLANE_W / TILE) * (PLANE_H / TILE) * NPLANES)   // 6144

typedef __fp16 half_t;
typedef __fp16 half2_t __attribute__((ext_vector_type(2)));
typedef __fp16 half4_t __attribute__((ext_vector_type(4)));

static constexpr float kC1s  = 81.0f * 0.0001f;   // 81*C1
static constexpr float kC2s  = 81.0f * 0.0009f;   // 81*C2
static constexpr float kEPSs = 6561.0f * 1e-8f;   // 81^2*eps
static constexpr float kINVN = 1.0f / 25165824.0f;

__global__ __launch_bounds__(256, 8) void loss_main(
    const float* __restrict__ X, const float* __restrict__ Y,
    float* __restrict__ part, unsigned* __restrict__ cnt,
    float* __restrict__ out)
{
    __shared__ __align__(16) half_t sxh[LDSH][LDSW];
    __shared__ __align__(16) half_t syh[LDSH][LDSW];
    __shared__ float red[8];
    __shared__ int amLast;

    const int tid   = threadIdx.x;
    const int tr0   = blockIdx.y * TILE;
    const int tc0   = blockIdx.x * TILE;
    const int plane = blockIdx.z;

    const float* __restrict__ xp = X + (size_t)plane * (PLANE_H * PLANE_W);
    const float* __restrict__ yp = Y + (size_t)plane * (PLANE_H * PLANE_W);

    float mse_acc = 0.0f, ssim_acc = 0.0f;

    // ---- staging: 5 uniform unrolled iterations; all loads issued first ----
    // quad i -> row hr = i/18, quad-col hq = i%18; global (tr0-1+hr, tc0-4+4*hq).
    float4 ldx[5], ldy[5];
#pragma unroll
    for (int u = 0; u < 5; ++u) {
        const int i  = tid + 256 * u;
        const int hr = i / 18;
        const int hq = i - hr * 18;
        const int gr = tr0 - 1 + hr;
        const int gc = tc0 - 4 + 4 * hq;
        ldx[u] = make_float4(0.f, 0.f, 0.f, 0.f);
        ldy[u] = make_float4(0.f, 0.f, 0.f, 0.f);
        const bool live = (u < 4) || (i < NQUADS);   // u<4 folds to true
        if (live && (unsigned)gr < PLANE_H && (unsigned)gc < PLANE_W) {
            const size_t g = (size_t)gr * PLANE_W + (size_t)gc;
            ldx[u] = *(const float4*)(xp + g);
            ldy[u] = *(const float4*)(yp + g);
        }
    }
#pragma unroll
    for (int u = 0; u < 5; ++u) {
        const int i  = tid + 256 * u;
        const int hr = i / 18;
        const int hq = i - hr * 18;
        if ((u < 4) || (i < NQUADS)) {
            // MSE from pristine f32: tile-interior quads only (each pixel once)
            if (hr >= 1 && hr <= TILE && hq >= 1 && hq <= 16) {
                const float d0 = ldx[u].x - ldy[u].x, d1 = ldx[u].y - ldy[u].y;
                const float d2 = ldx[u].z - ldy[u].z, d3 = ldx[u].w - ldy[u].w;
                mse_acc += d0 * d0 + d1 * d1 + d2 * d2 + d3 * d3;
            }
            const half2_t xl = __builtin_amdgcn_cvt_pkrtz(ldx[u].x, ldx[u].y);
            const half2_t xh = __builtin_amdgcn_cvt_pkrtz(ldx[u].z, ldx[u].w);
            const half2_t yl = __builtin_amdgcn_cvt_pkrtz(ldy[u].x, ldy[u].y);
            const half2_t yh = __builtin_amdgcn_cvt_pkrtz(ldy[u].z, ldy[u].w);
            const half4_t x4 = {xl.x, xl.y, xh.x, xh.y};
            const half4_t y4 = {yl.x, yl.y, yh.x, yh.y};
            *(half4_t*)&sxh[hr][4 * hq] = x4;
            *(half4_t*)&syh[hr][4 * hq] = y4;
        }
    }
    __syncthreads();

    // ---- each thread: 4x4 pixel patch ----
    // pixel (pr, pc) -> LDS (pr+1, pc+4). Window cols = LDS 4q+3 .. 4q+8.
    const int q   = tid & 15;
    const int pr0 = (tid >> 4) * 4;
    const int cb  = 4 * q;

    // ring[row%3][qty][pair]  qty: 0=x 1=y 2=xx+yy 3=xy  (f16-packed row sums)
    half2_t ring[3][4][2];

#pragma unroll
    for (int j = 0; j < 6; ++j) {
        const int R = pr0 + j;
        const half_t* __restrict__ rx = &sxh[R][0];
        const half_t* __restrict__ ry = &syh[R][0];
        const half2_t ax = *(const half2_t*)&rx[cb + 2];   // b32
        const half4_t bx = *(const half4_t*)&rx[cb + 4];   // b64
        const half2_t cx = *(const half2_t*)&rx[cb + 8];   // b32
        const half2_t ay = *(const half2_t*)&ry[cb + 2];
        const half4_t by = *(const half4_t*)&ry[cb + 4];
        const half2_t cy = *(const half2_t*)&ry[cb + 8];

        const float ex0 = (float)ax.y, ex1 = (float)bx.x, ex2 = (float)bx.y,
                    ex3 = (float)bx.z, ex4 = (float)bx.w, ex5 = (float)cx.x;
        const float ey0 = (float)ay.y, ey1 = (float)by.x, ey2 = (float)by.y,
                    ey3 = (float)by.z, ey4 = (float)by.w, ey5 = (float)cy.x;

        half2_t (&slot)[4][2] = ring[j % 3];   // compile-time after unroll

        // horizontal 3-sums (f32) -> packed f16 ring
        {
            const float t12 = ex1 + ex2, t23 = ex2 + ex3, t34 = ex3 + ex4;
            slot[0][0] = __builtin_amdgcn_cvt_pkrtz(ex0 + t12, t12 + ex3);
            slot[0][1] = __builtin_amdgcn_cvt_pkrtz(t23 + ex4, t34 + ex5);
        }
        {
            const float t12 = ey1 + ey2, t23 = ey2 + ey3, t34 = ey3 + ey4;
            slot[1][0] = __builtin_amdgcn_cvt_pkrtz(ey0 + t12, t12 + ey3);
            slot[1][1] = __builtin_amdgcn_cvt_pkrtz(t23 + ey4, t34 + ey5);
        }
        {
            const float s0 = __builtin_fmaf(ex0, ex0, ey0 * ey0);
            const float s1 = __builtin_fmaf(ex1, ex1, ey1 * ey1);
            const float s2 = __builtin_fmaf(ex2, ex2, ey2 * ey2);
            const float s3 = __builtin_fmaf(ex3, ex3, ey3 * ey3);
            const float s4 = __builtin_fmaf(ex4, ex4, ey4 * ey4);
            const float s5 = __builtin_fmaf(ex5, ex5, ey5 * ey5);
            const float t12 = s1 + s2, t23 = s2 + s3, t34 = s3 + s4;
            slot[2][0] = __builtin_amdgcn_cvt_pkrtz(s0 + t12, t12 + s3);
            slot[2][1] = __builtin_amdgcn_cvt_pkrtz(t23 + s4, t34 + s5);
        }
        {
            const float p0 = ex0 * ey0, p1 = ex1 * ey1, p2 = ex2 * ey2;
            const float p3 = ex3 * ey3, p4 = ex4 * ey4, p5 = ex5 * ey5;
            const float t12 = p1 + p2, t23 = p2 + p3, t34 = p3 + p4;
            slot[3][0] = __builtin_amdgcn_cvt_pkrtz(p0 + t12, t12 + p3);
            slot[3][1] = __builtin_amdgcn_cvt_pkrtz(t23 + p4, t34 + p5);
        }

        if (j >= 2) {
            // vertical 3-sums: v_pk_add_f16 over all three ring slots
            const half2_t sx01 = ring[0][0][0] + ring[1][0][0] + ring[2][0][0];
            const half2_t sx23 = ring[0][0][1] + ring[1][0][1] + ring[2][0][1];
            const half2_t sy01 = ring[0][1][0] + ring[1][1][0] + ring[2][1][0];
            const half2_t sy23 = ring[0][1][1] + ring[1][1][1] + ring[2][1][1];
            const half2_t ss01 = ring[0][2][0] + ring[1][2][0] + ring[2][2][0];
            const half2_t ss23 = ring[0][2][1] + ring[1][2][1] + ring[2][2][1];
            const half2_t sp01 = ring[0][3][0] + ring[1][3][0] + ring[2][3][0];
            const half2_t sp23 = ring[0][3][1] + ring[1][3][1] + ring[2][3][1];

            const float S_x[4] = {(float)sx01.x, (float)sx01.y, (float)sx23.x, (float)sx23.y};
            const float S_y[4] = {(float)sy01.x, (float)sy01.y, (float)sy23.x, (float)sy23.y};
            const float S_s[4] = {(float)ss01.x, (float)ss01.y, (float)ss23.x, (float)ss23.y};
            const float S_p[4] = {(float)sp01.x, (float)sp01.y, (float)sp23.x, (float)sp23.y};

#pragma unroll
            for (int c = 0; c < 4; ++c) {
                // scaled-domain SSIM: window sums x9 (mu x9); 81^2 cancels in
                // num/den; eps scales by 81^2.
                const float P   = S_x[c] * S_y[c];
                const float Q   = __builtin_fmaf(S_x[c], S_x[c], S_y[c] * S_y[c]);
                const float t1  = __builtin_fmaf(2.0f, P, kC1s);
                const float t3  = __builtin_fmaf(18.0f, S_p[c],
                                      __builtin_fmaf(-2.0f, P, kC2s));
                const float num = t1 * t3;
                const float u2  = __builtin_fmaf(9.0f, S_s[c], -Q);  // >= 0 (C-S)
                const float den = __builtin_fmaf(Q + kC1s, u2 + kC2s, kEPSs);
                ssim_acc = __builtin_fmaf(num, __builtin_amdgcn_rcpf(den), ssim_acc);
            }
        }
    }

    // ---- block reduction ----
#pragma unroll
    for (int off = 32; off > 0; off >>= 1) {
        mse_acc  += __shfl_down(mse_acc, off, 64);
        ssim_acc += __shfl_down(ssim_acc, off, 64);
    }
    const int wave = tid >> 6;
    if ((tid & 63) == 0) {
        red[wave]     = mse_acc;
        red[4 + wave] = ssim_acc;
    }
    __syncthreads();

    const int bid = (blockIdx.z * gridDim.y + blockIdx.y) * gridDim.x + blockIdx.x;
    if (tid == 0) {
        const float m = red[0] + red[1] + red[2] + red[3];
        const float s = red[4] + red[5] + red[6] + red[7];
        // agent-scope atomic stores: coherent across XCDs for the last block
        __hip_atomic_store(&part[bid], m, __ATOMIC_RELAXED, __HIP_MEMORY_SCOPE_AGENT);
        __hip_atomic_store(&part[NBLOCKS + bid], s, __ATOMIC_RELAXED, __HIP_MEMORY_SCOPE_AGENT);
        const unsigned old = __hip_atomic_fetch_add(cnt, 1u, __ATOMIC_ACQ_REL,
                                                    __HIP_MEMORY_SCOPE_AGENT);
        amLast = (old == (unsigned)(NBLOCKS - 1));
    }
    __syncthreads();

    // ---- last block: deterministic final reduce (replaces 2 kernels) ----
    if (amLast) {
        float m = 0.0f, s = 0.0f;
#pragma unroll 4
        for (int i = tid; i < NBLOCKS; i += 256) {   // 24 iters/thread
            m += __hip_atomic_load(&part[i], __ATOMIC_RELAXED, __HIP_MEMORY_SCOPE_AGENT);
            s += __hip_atomic_load(&part[NBLOCKS + i], __ATOMIC_RELAXED, __HIP_MEMORY_SCOPE_AGENT);
        }
#pragma unroll
        for (int off = 32; off > 0; off >>= 1) {
            m += __shfl_down(m, off, 64);
            s += __shfl_down(s, off, 64);
        }
        if ((tid & 63) == 0) {
            red[wave]     = m;
            red[4 + wave] = s;
        }
        __syncthreads();
        if (tid == 0) {
            const float mse       = (red[0] + red[1] + red[2] + red[3]) * kINVN;
            const float ssim_mean = (red[4] + red[5] + red[6] + red[7]) * kINVN;
            out[0] = 0.8f * mse + 0.2f * (1.0f - ssim_mean);
        }
    }
}

extern "C" void kernel_launch(void* const* d_in, const int* in_sizes, int n_in,
                              void* d_out, int out_size, void* d_ws, size_t ws_size,
                              hipStream_t stream)
{
    const float* x = (const float*)d_in[0];   // reconstruction
    const float* y = (const float*)d_in[1];   // target
    float* out  = (float*)d_out;
    float* part = (float*)d_ws;               // 2*NBLOCKS floats
    unsigned* cnt = (unsigned*)(part + 2 * NBLOCKS);

    hipMemsetAsync(cnt, 0, sizeof(unsigned), stream);   // reset done-counter
    dim3 grid(PLANE_W / TILE, PLANE_H / TILE, NPLANES); // 8 x 8 x 96 = 6144
    loss_main<<<grid, 256, 0, stream>>>(x, y, part, cnt, out);
}

// Round 2
// 227.559 us; speedup vs baseline: 2.2489x; 2.2489x over previous
//
#include <hip/hip_runtime.h>

// EnhancedReconstructionLoss: loss = 0.8*mean((x-y)^2) + 0.2*(1 - mean(ssim_map))
// ssim from 3x3 avg pools (stride 1, zero-pad 1, divisor always 9).
// Shapes: (32,3,512,512) fp32 -> 96 planes of 512x512.
//
// R2: atomics -> per-block partial stores (639 -> 101 us main).
// R3: parallel 2-stage reduce; rcp not divide (96 us).
// R4: 64x64 f32 LDS tile, 4x4/thread (91 us).
// R6: f16 LDS staging (19 KB/block). 89 us, VALUBusy 43%, HBM 28%.
// R8 FAILED: fused last-block finish w/ agent-scope ACQ_REL fetch_add ->
//     6144 serialized cache-maintenance RMWs = 372 us kernel. VALU-busy
//     TIME unchanged (38.9 -> 36.5 us) => f16 ring neutral, batching no-op.
// R9 (this): revert to 3-kernel reduce. Attack the phase-lock (VALU 43% +
//     HBM 28%, neither saturated): T14 async-STAGE split. Tile in 2 row
//     halves: stage A (LDS rows 0..33), ISSUE B loads into 16 held VGPRs
//     (sched_barrier(0) pins them - R8 showed compiler sinks otherwise),
//     barrier, compute pass A (pixel rows 0..31) while B flies, cvt+write
//     B, barrier, pass B. Patches 2x4 px, two passes, all threads active.

#define PLANE_H 512
#define PLANE_W 512
#define NPLANES 96
#define TILE    64
#define LDSH    66                  // TILE + 2 halo rows
#define LDSW    72                  // halfs/row; 144 B stride
#define ROWS_A  34                  // LDS rows 0..33 staged up-front
#define QUADS_A (ROWS_A * 18)       // 612
#define QUADS_B ((LDSH - ROWS_A) * 18)   // 576 (rows 34..65)
#define NBLOCKS ((PLANE_W / TILE) * (PLANE_H / TILE) * NPLANES)   // 6144
#define NB1     (NBLOCKS / 256)     // 24

typedef __fp16 half_t;
typedef __fp16 half2_t __attribute__((ext_vector_type(2)));
typedef __fp16 half4_t __attribute__((ext_vector_type(4)));

static constexpr float kC1s  = 81.0f * 0.0001f;   // 81*C1
static constexpr float kC2s  = 81.0f * 0.0009f;   // 81*C2
static constexpr float kEPSs = 6561.0f * 1e-8f;   // 81^2*eps
static constexpr float kINVN = 1.0f / 25165824.0f;

// cvt f32 quad -> f16 quad + LDS write at [hr][4*hq]
__device__ __forceinline__ void stage_write(
    half_t (*sxh)[LDSW], half_t (*syh)[LDSW],
    int hr, int hq, const float4& vx, const float4& vy)
{
    const half2_t xl = __builtin_amdgcn_cvt_pkrtz(vx.x, vx.y);
    const half2_t xh = __builtin_amdgcn_cvt_pkrtz(vx.z, vx.w);
    const half2_t yl = __builtin_amdgcn_cvt_pkrtz(vy.x, vy.y);
    const half2_t yh = __builtin_amdgcn_cvt_pkrtz(vy.z, vy.w);
    const half4_t x4 = {xl.x, xl.y, xh.x, xh.y};
    const half4_t y4 = {yl.x, yl.y, yh.x, yh.y};
    *(half4_t*)&sxh[hr][4 * hq] = x4;
    *(half4_t*)&syh[hr][4 * hq] = y4;
}

// one 4-row pass: outputs pixel rows pr0, pr0+1 (LDS rows pr0..pr0+3),
// 4 columns starting at pixel col 4q (LDS halfs cb+3..cb+8 windows).
__device__ __forceinline__ void ssim_pass(
    const half_t (*sxh)[LDSW], const half_t (*syh)[LDSW],
    const int pr0, const int cb, float& ssim_acc)
{
    // ring[row%3][qty][pair]  qty: 0=x 1=y 2=xx+yy 3=xy  (f16-packed row sums)
    half2_t ring[3][4][2];

#pragma unroll
    for (int j = 0; j < 4; ++j) {
        const int R = pr0 + j;
        const half_t* __restrict__ rx = &sxh[R][0];
        const half_t* __restrict__ ry = &syh[R][0];
        const half2_t ax = *(const half2_t*)&rx[cb + 2];   // b32
        const half4_t bx = *(const half4_t*)&rx[cb + 4];   // b64
        const half2_t cx = *(const half2_t*)&rx[cb + 8];   // b32
        const half2_t ay = *(const half2_t*)&ry[cb + 2];
        const half4_t by = *(const half4_t*)&ry[cb + 4];
        const half2_t cy = *(const half2_t*)&ry[cb + 8];

        const float ex0 = (float)ax.y, ex1 = (float)bx.x, ex2 = (float)bx.y,
                    ex3 = (float)bx.z, ex4 = (float)bx.w, ex5 = (float)cx.x;
        const float ey0 = (float)ay.y, ey1 = (float)by.x, ey2 = (float)by.y,
                    ey3 = (float)by.z, ey4 = (float)by.w, ey5 = (float)cy.x;

        half2_t (&slot)[4][2] = ring[j % 3];   // static after unroll

        {
            const float t12 = ex1 + ex2, t23 = ex2 + ex3, t34 = ex3 + ex4;
            slot[0][0] = __builtin_amdgcn_cvt_pkrtz(ex0 + t12, t12 + ex3);
            slot[0][1] = __builtin_amdgcn_cvt_pkrtz(t23 + ex4, t34 + ex5);
        }
        {
            const float t12 = ey1 + ey2, t23 = ey2 + ey3, t34 = ey3 + ey4;
            slot[1][0] = __builtin_amdgcn_cvt_pkrtz(ey0 + t12, t12 + ey3);
            slot[1][1] = __builtin_amdgcn_cvt_pkrtz(t23 + ey4, t34 + ey5);
        }
        {
            const float s0 = __builtin_fmaf(ex0, ex0, ey0 * ey0);
            const float s1 = __builtin_fmaf(ex1, ex1, ey1 * ey1);
            const float s2 = __builtin_fmaf(ex2, ex2, ey2 * ey2);
            const float s3 = __builtin_fmaf(ex3, ex3, ey3 * ey3);
            const float s4 = __builtin_fmaf(ex4, ex4, ey4 * ey4);
            const float s5 = __builtin_fmaf(ex5, ex5, ey5 * ey5);
            const float t12 = s1 + s2, t23 = s2 + s3, t34 = s3 + s4;
            slot[2][0] = __builtin_amdgcn_cvt_pkrtz(s0 + t12, t12 + s3);
            slot[2][1] = __builtin_amdgcn_cvt_pkrtz(t23 + s4, t34 + s5);
        }
        {
            const float p0 = ex0 * ey0, p1 = ex1 * ey1, p2 = ex2 * ey2;
            const float p3 = ex3 * ey3, p4 = ex4 * ey4, p5 = ex5 * ey5;
            const float t12 = p1 + p2, t23 = p2 + p3, t34 = p3 + p4;
            slot[3][0] = __builtin_amdgcn_cvt_pkrtz(p0 + t12, t12 + p3);
            slot[3][1] = __builtin_amdgcn_cvt_pkrtz(t23 + p4, t34 + p5);
        }

        if (j >= 2) {
            const half2_t sx01 = ring[0][0][0] + ring[1][0][0] + ring[2][0][0];
            const half2_t sx23 = ring[0][0][1] + ring[1][0][1] + ring[2][0][1];
            const half2_t sy01 = ring[0][1][0] + ring[1][1][0] + ring[2][1][0];
            const half2_t sy23 = ring[0][1][1] + ring[1][1][1] + ring[2][1][1];
            const half2_t ss01 = ring[0][2][0] + ring[1][2][0] + ring[2][2][0];
            const half2_t ss23 = ring[0][2][1] + ring[1][2][1] + ring[2][2][1];
            const half2_t sp01 = ring[0][3][0] + ring[1][3][0] + ring[2][3][0];
            const half2_t sp23 = ring[0][3][1] + ring[1][3][1] + ring[2][3][1];

            const float S_x[4] = {(float)sx01.x, (float)sx01.y, (float)sx23.x, (float)sx23.y};
            const float S_y[4] = {(float)sy01.x, (float)sy01.y, (float)sy23.x, (float)sy23.y};
            const float S_s[4] = {(float)ss01.x, (float)ss01.y, (float)ss23.x, (float)ss23.y};
            const float S_p[4] = {(float)sp01.x, (float)sp01.y, (float)sp23.x, (float)sp23.y};

#pragma unroll
            for (int c = 0; c < 4; ++c) {
                // scaled-domain SSIM: window sums x9 (mu x9); 81^2 cancels in
                // num/den; eps scales by 81^2.
                const float P   = S_x[c] * S_y[c];
                const float Q   = __builtin_fmaf(S_x[c], S_x[c], S_y[c] * S_y[c]);
                const float t1  = __builtin_fmaf(2.0f, P, kC1s);
                const float t3  = __builtin_fmaf(18.0f, S_p[c],
                                      __builtin_fmaf(-2.0f, P, kC2s));
                const float num = t1 * t3;
                const float u2  = __builtin_fmaf(9.0f, S_s[c], -Q);  // >= 0 (C-S)
                const float den = __builtin_fmaf(Q + kC1s, u2 + kC2s, kEPSs);
                ssim_acc = __builtin_fmaf(num, __builtin_amdgcn_rcpf(den), ssim_acc);
            }
        }
    }
}

__global__ __launch_bounds__(256, 8) void loss_main(
    const float* __restrict__ X, const float* __restrict__ Y,
    float* __restrict__ part)
{
    __shared__ __align__(16) half_t sxh[LDSH][LDSW];
    __shared__ __align__(16) half_t syh[LDSH][LDSW];

    const int tid   = threadIdx.x;
    const int tr0   = blockIdx.y * TILE;
    const int tc0   = blockIdx.x * TILE;
    const int plane = blockIdx.z;

    const float* __restrict__ xp = X + (size_t)plane * (PLANE_H * PLANE_W);
    const float* __restrict__ yp = Y + (size_t)plane * (PLANE_H * PLANE_W);

    float mse_acc = 0.0f, ssim_acc = 0.0f;

    // ---- phase 1: stage A (rows 0..33) load+cvt+write, MSE from f32 ----
    for (int i = tid; i < QUADS_A; i += 256) {
        const int hr = i / 18;
        const int hq = i - hr * 18;
        const int gr = tr0 - 1 + hr;
        const int gc = tc0 - 4 + 4 * hq;
        float4 vx = make_float4(0.f, 0.f, 0.f, 0.f);
        float4 vy = make_float4(0.f, 0.f, 0.f, 0.f);
        if ((unsigned)gr < PLANE_H && (unsigned)gc < PLANE_W) {
            const size_t g = (size_t)gr * PLANE_W + (size_t)gc;
            vx = *(const float4*)(xp + g);
            vy = *(const float4*)(yp + g);
        }
        if (hr >= 1 && hq >= 1 && hq <= 16) {     // hr<=33: always interior
            const float d0 = vx.x - vy.x, d1 = vx.y - vy.y;
            const float d2 = vx.z - vy.z, d3 = vx.w - vy.w;
            mse_acc += d0 * d0 + d1 * d1 + d2 * d2 + d3 * d3;
        }
        stage_write(sxh, syh, hr, hq, vx, vy);
    }

    // ---- phase 2: ISSUE bottom-half loads (rows 34..62 slice, 512 quads) ----
    // held rows hr=34..62: always in-plane vertically; only gc needs masking.
    float4 bxr[2], byr[2];
#pragma unroll
    for (int u = 0; u < 2; ++u) {
        const int ib = tid + 256 * u;
        const int hr = ROWS_A + ib / 18;
        const int hq = ib - (ib / 18) * 18;
        const int gr = tr0 - 1 + hr;
        const int gc = tc0 - 4 + 4 * hq;
        bxr[u] = make_float4(0.f, 0.f, 0.f, 0.f);
        byr[u] = make_float4(0.f, 0.f, 0.f, 0.f);
        if ((unsigned)gc < PLANE_W) {
            const size_t g = (size_t)gr * PLANE_W + (size_t)gc;
            bxr[u] = *(const float4*)(xp + g);
            byr[u] = *(const float4*)(yp + g);
        }
    }
    __builtin_amdgcn_sched_barrier(0);   // pin the issue point (R8: compiler sinks)

    __syncthreads();                     // A visible

    // ---- phase 3: pass A (pixel rows 0..31) overlaps B's HBM latency ----
    const int q   = tid & 15;
    const int cb  = 4 * q;
    const int rg  = tid >> 4;            // 0..15
    ssim_pass(sxh, syh, 2 * rg, cb, ssim_acc);

    // ---- phase 4: write B from held regs + tail (64 quads, wave 0) ----
#pragma unroll
    for (int u = 0; u < 2; ++u) {
        const int ib = tid + 256 * u;
        const int hr = ROWS_A + ib / 18;
        const int hq = ib - (ib / 18) * 18;
        if (hq >= 1 && hq <= 16) {       // hr 34..62: always interior
            const float d0 = bxr[u].x - byr[u].x, d1 = bxr[u].y - byr[u].y;
            const float d2 = bxr[u].z - byr[u].z, d3 = bxr[u].w - byr[u].w;
            mse_acc += d0 * d0 + d1 * d1 + d2 * d2 + d3 * d3;
        }
        stage_write(sxh, syh, hr, hq, bxr[u], byr[u]);
    }
    {
        const int ib = tid + 512;
        if (ib < QUADS_B) {              // 64 quads: rows 62..65 remainder
            const int hr = ROWS_A + ib / 18;
            const int hq = ib - (ib / 18) * 18;
            const int gr = tr0 - 1 + hr;
            const int gc = tc0 - 4 + 4 * hq;
            float4 vx = make_float4(0.f, 0.f, 0.f, 0.f);
            float4 vy = make_float4(0.f, 0.f, 0.f, 0.f);
            if ((unsigned)gr < PLANE_H && (unsigned)gc < PLANE_W) {
                const size_t g = (size_t)gr * PLANE_W + (size_t)gc;
                vx = *(const float4*)(xp + g);
                vy = *(const float4*)(yp + g);
            }
            if (hr <= TILE && hq >= 1 && hq <= 16) {   // hr 65 is halo
                const float d0 = vx.x - vy.x, d1 = vx.y - vy.y;
                const float d2 = vx.z - vy.z, d3 = vx.w - vy.w;
                mse_acc += d0 * d0 + d1 * d1 + d2 * d2 + d3 * d3;
            }
            stage_write(sxh, syh, hr, hq, vx, vy);
        }
    }
    __syncthreads();                     // B visible

    // ---- phase 5: pass B (pixel rows 32..63; rows 32,33 reuse A region) ----
    ssim_pass(sxh, syh, 32 + 2 * rg, cb, ssim_acc);

    // ---- block reduction ----
#pragma unroll
    for (int off = 32; off > 0; off >>= 1) {
        mse_acc  += __shfl_down(mse_acc, off, 64);
        ssim_acc += __shfl_down(ssim_acc, off, 64);
    }
    __shared__ float red[8];
    const int wave = tid >> 6;
    if ((tid & 63) == 0) {
        red[wave]     = mse_acc;
        red[4 + wave] = ssim_acc;
    }
    __syncthreads();
    if (tid == 0) {
        const int bid = (blockIdx.z * gridDim.y + blockIdx.y) * gridDim.x + blockIdx.x;
        part[bid]           = red[0] + red[1] + red[2] + red[3];
        part[NBLOCKS + bid] = red[4] + red[5] + red[6] + red[7];
    }
}

__global__ __launch_bounds__(256) void loss_reduce1(
    const float* __restrict__ part, float* __restrict__ part2)
{
    const int tid = threadIdx.x;
    const int i   = blockIdx.x * 256 + tid;
    float m = part[i];
    float s = part[NBLOCKS + i];
#pragma unroll
    for (int off = 32; off > 0; off >>= 1) {
        m += __shfl_down(m, off, 64);
        s += __shfl_down(s, off, 64);
    }
    __shared__ float red[8];
    const int wave = tid >> 6;
    if ((tid & 63) == 0) {
        red[wave]     = m;
        red[4 + wave] = s;
    }
    __syncthreads();
    if (tid == 0) {
        part2[blockIdx.x]       = red[0] + red[1] + red[2] + red[3];
        part2[NB1 + blockIdx.x] = red[4] + red[5] + red[6] + red[7];
    }
}

__global__ __launch_bounds__(64) void loss_final(
    const float* __restrict__ part2, float* __restrict__ out)
{
    const int tid = threadIdx.x;
    float m = 0.0f, s = 0.0f;
    if (tid < NB1) {
        m = part2[tid];
        s = part2[NB1 + tid];
    }
#pragma unroll
    for (int off = 32; off > 0; off >>= 1) {
        m += __shfl_down(m, off, 64);
        s += __shfl_down(s, off, 64);
    }
    if (tid == 0) {
        const float mse       = m * kINVN;
        const float ssim_mean = s * kINVN;
        out[0] = 0.8f * mse + 0.2f * (1.0f - ssim_mean);
    }
}

extern "C" void kernel_launch(void* const* d_in, const int* in_sizes, int n_in,
                              void* d_out, int out_size, void* d_ws, size_t ws_size,
                              hipStream_t stream)
{
    const float* x = (const float*)d_in[0];   // reconstruction
    const float* y = (const float*)d_in[1];   // target
    float* out   = (float*)d_out;
    float* part  = (float*)d_ws;              // 2*NBLOCKS floats
    float* part2 = part + 2 * NBLOCKS;        // 2*NB1 floats

    dim3 grid(PLANE_W / TILE, PLANE_H / TILE, NPLANES);   // 8 x 8 x 96 = 6144
    loss_main<<<grid, 256, 0, stream>>>(x, y, part);
    loss_reduce1<<<NB1, 256, 0, stream>>>(part, part2);
    loss_final<<<1, 64, 0, stream>>>(part2, out);
}